// Round 17
// baseline (85.873 us; speedup 1.0000x reference)
//
#include <hip/hip_runtime.h>
#include <hip/hip_bf16.h>

// Problem constants
#define B_    64
#define S_    512
#define L_    256
#define D_    768      // K of GEMM1
#define RED_  400
#define REDP_ 512      // padded N of GEMM1 / K-stride of GEMM23
#define KEFF_ 416      // effective K of GEMM23 (13 k-tiles; h cols 400.. are 0)
#define HID_  100
#define HIDP_ 128      // padded N of GEMM23 / K of aff+triplet
#define TAGS_ 5
#define POL_  4
#define NBI_  512      // aff padded N (4 * 128)
#define NAO_  256      // fused ap|op GEMM N
#define BL_   (B_ * L_)  // 16384

typedef __attribute__((ext_vector_type(8))) short short8;
typedef __attribute__((ext_vector_type(4))) float f32x4;
typedef __attribute__((ext_vector_type(4))) unsigned short u16x4;

#define GLOAD_LDS16(gp, lp) __builtin_amdgcn_global_load_lds( \
    (const __attribute__((address_space(1))) void*)(gp),      \
    (__attribute__((address_space(3))) void*)(lp), 16, 0, 0)

__device__ inline float bf2f(unsigned short u) {
    union { unsigned int i; float f; } c; c.i = ((unsigned)u) << 16; return c.f;
}
__device__ inline unsigned short f2bf(float f) {
    __hip_bfloat16 h = __float2bfloat16(f);
    unsigned short u;
    __builtin_memcpy(&u, &h, 2);
    return u;
}

// ---------------------------------------------------------------------------
// 0+1) FRONT: blocks [0,4096) = segment mean (4 rows/block, float4 loads);
//      blocks [4096, ...) = weight/bias prep.
// ---------------------------------------------------------------------------
#define SZ0 393216
#define SZ1 131072
#define SZ2 65536
#define SZ3 512
#define SZ4 256
#define PREP_TOT (SZ0 + SZ1 + SZ2 + SZ3 + SZ4)
#define SEG_BLOCKS (BL_ / 4)
#define PREP_BLOCKS ((PREP_TOT + 255) / 256)

__global__ __launch_bounds__(256) void front_kernel(
    const float* __restrict__ bert, const int* __restrict__ pos,
    unsigned short* __restrict__ pooled,
    const float* __restrict__ W_reduc, const float* __restrict__ b_reduc,
    const float* __restrict__ W_ap, const float* __restrict__ b_ap,
    const float* __restrict__ W_op, const float* __restrict__ b_op,
    const float* __restrict__ W_bi,
    unsigned short* __restrict__ WtR, unsigned short* __restrict__ WtAO,
    unsigned short* __restrict__ WtBi,
    float* __restrict__ bR, float* __restrict__ bAO, float* __restrict__ bBi)
{
    if (blockIdx.x < SEG_BLOCKS) {
        int r  = threadIdx.x >> 6;
        int l  = threadIdx.x & 63;
        int bl = blockIdx.x * 4 + r;
        int b  = bl >> 8;
        int s  = pos[bl * 2 + 0];
        int e  = pos[bl * 2 + 1];
        int len = e - s + 1;                // 1 or 2
        const float* v0 = bert + ((size_t)b * S_ + s) * D_;
        float inv = (len == 2) ? 0.5f : 1.0f;
        unsigned short* outp = pooled + (size_t)bl * D_;
        #pragma unroll
        for (int c = 0; c < 3; ++c) {
            int d = l * 4 + c * 256;
            f32x4 x = *(const f32x4*)(v0 + d);
            if (len == 2) {
                f32x4 y = *(const f32x4*)(v0 + D_ + d);
                x += y;
            }
            u16x4 o;
            #pragma unroll
            for (int j = 0; j < 4; ++j) o[j] = f2bf(x[j] * inv);
            *(u16x4*)(outp + d) = o;
        }
        return;
    }

    int idx = (blockIdx.x - SEG_BLOCKS) * 256 + threadIdx.x;
    if (idx < SZ0) {
        int n = idx / D_, k = idx - n * D_;
        float v = (n < RED_) ? W_reduc[(size_t)k * RED_ + n] : 0.f;
        WtR[idx] = f2bf(v);
    } else if (idx < SZ0 + SZ1) {
        int i = idx - SZ0;
        int n = i >> 9, k = i & 511;
        float v = 0.f;
        if (k < RED_) {
            if (n < HID_)                      v = W_ap[(size_t)k * HID_ + n];
            else if (n >= 128 && n < 128+HID_) v = W_op[(size_t)k * HID_ + (n-128)];
        }
        WtAO[i] = f2bf(v);
    } else if (idx < SZ0 + SZ1 + SZ2) {
        int i = idx - SZ0 - SZ1;
        int n = i >> 7, k = i & 127;
        int p = n >> 7, h = n & 127;
        float v = (h < HID_ && k < HID_) ? W_bi[(size_t)k * RED_ + p * HID_ + h] : 0.f;
        WtBi[i] = f2bf(v);
        if (k == 0) bBi[n] = (h < HID_) ? W_bi[(size_t)HID_ * RED_ + p * HID_ + h] : 0.f;
    } else if (idx < SZ0 + SZ1 + SZ2 + SZ3) {
        int n = idx - SZ0 - SZ1 - SZ2;
        bR[n] = (n < RED_) ? b_reduc[n] : 0.f;
    } else if (idx < PREP_TOT) {
        int n = idx - SZ0 - SZ1 - SZ2 - SZ3;
        bAO[n] = (n < 128) ? ((n < HID_) ? b_ap[n] : 0.f)
                           : (((n-128) < HID_) ? b_op[n-128] : 0.f);
    }
}

// ---------------------------------------------------------------------------
// 2) GEMM1, pure bf16, high occupancy:
//    h = relu( pooled[16384,768] @ WtR[512,768]^T + bR ) -> bf16
// Tile 64 rows x 128 cols; grid (256, 4) = 1024 blocks = 4 blocks/CU.
// LDS 24 KB (2 x (A 4KB + B 8KB)); both operands via global_load_lds.
// Waves 2x2: each 32 rows x 64 cols, acc[2][4].
// ---------------------------------------------------------------------------
__global__ __launch_bounds__(256) void gemm1_kernel(
    const short* __restrict__ A, const short* __restrict__ Bt,
    const float* __restrict__ bias, unsigned short* __restrict__ Co)
{
    // per buf: A 64x32 (2048 shorts) | B 128x32 (4096 shorts)
    __shared__ __align__(16) short lds[2][6144];

    const int t  = threadIdx.x;
    const int wv = t >> 6;
    const int ln = t & 63;
    const int wm = wv >> 1;        // row half (32 rows)
    const int wn = wv & 1;         // col half (64 cols)
    const int bm = blockIdx.x * 64;
    const int bn = blockIdx.y * 128;

    const int srow = t >> 2;       // 0..63
    const int skc  = (t & 3) * 8;  // k offset (elements)

    f32x4 acc[2][4] = {};
    const int NT = D_ >> 5;   // 24

    // ---- prologue: stage kt=0 into buf 0 ----
    {
        const short* gA = A + (size_t)(bm + srow) * D_ + skc;
        GLOAD_LDS16(gA, &lds[0][srow * 32 + skc]);
        #pragma unroll
        for (int q = 0; q < 2; ++q) {
            const short* gB = Bt + (size_t)(bn + q * 64 + srow) * D_ + skc;
            GLOAD_LDS16(gB, &lds[0][2048 + q * 2048 + wv * 512]);
        }
    }
    __syncthreads();

    int cur = 0;
    const int lr = ln & 15;
    const int lk = (ln >> 4) * 8;

    for (int kt = 0; kt < NT; ++kt) {
        if (kt + 1 < NT) {
            int k0 = (kt + 1) << 5;
            const short* gA = A + (size_t)(bm + srow) * D_ + k0 + skc;
            GLOAD_LDS16(gA, &lds[cur ^ 1][srow * 32 + skc]);
            #pragma unroll
            for (int q = 0; q < 2; ++q) {
                const short* gB = Bt + (size_t)(bn + q * 64 + srow) * D_ + k0 + skc;
                GLOAD_LDS16(gB, &lds[cur ^ 1][2048 + q * 2048 + wv * 512]);
            }
        }

        const short* As = &lds[cur][0];
        const short* Bs = &lds[cur][2048];
        short8 a[2], b[4];
        #pragma unroll
        for (int fi = 0; fi < 2; ++fi)
            a[fi] = *(const short8*)(As + (wm * 32 + fi * 16 + lr) * 32 + lk);
        #pragma unroll
        for (int fj = 0; fj < 4; ++fj)
            b[fj] = *(const short8*)(Bs + (wn * 64 + fj * 16 + lr) * 32 + lk);
        #pragma unroll
        for (int fi = 0; fi < 2; ++fi)
            #pragma unroll
            for (int fj = 0; fj < 4; ++fj)
                acc[fi][fj] = __builtin_amdgcn_mfma_f32_16x16x32_bf16(
                    a[fi], b[fj], acc[fi][fj], 0, 0, 0);

        __syncthreads();
        cur ^= 1;
    }

    const int row0 = bm + wm * 32 + (ln >> 4) * 4;
    const int col0 = bn + wn * 64 + lr;
    #pragma unroll
    for (int fi = 0; fi < 2; ++fi)
        #pragma unroll
        for (int rr = 0; rr < 4; ++rr) {
            int row = row0 + fi * 16 + rr;
            #pragma unroll
            for (int fj = 0; fj < 4; ++fj) {
                int col = col0 + fj * 16;
                float v = fmaxf(acc[fi][fj][rr] + bias[col], 0.f);
                Co[(size_t)row * REDP_ + col] = f2bf(v);
            }
        }
}

// ---------------------------------------------------------------------------
// 3) GEMM23 + tag heads (unchanged). grid (128, 2).
// ---------------------------------------------------------------------------
__global__ __launch_bounds__(256) void gemm23_tag_kernel(
    const short* __restrict__ A, const short* __restrict__ Bt,
    const float* __restrict__ bias,
    unsigned short* __restrict__ apOut, unsigned short* __restrict__ opOut,
    const float* __restrict__ Wap_tag, const float* __restrict__ bap_tag,
    const float* __restrict__ Wop_tag, const float* __restrict__ bop_tag,
    float* __restrict__ out_tag)
{
    __shared__ __align__(16) short lds[2][8192];
    __shared__ float tagf[128 * 101];
    __shared__ float Wtag[HID_ * TAGS_];
    __shared__ float Btag[TAGS_];

    const int t  = threadIdx.x;
    const int wv = t >> 6;
    const int ln = t & 63;
    const int wm = wv >> 1;
    const int wn = wv & 1;
    const int bm = blockIdx.x * 128;
    const int bn = blockIdx.y * 128;
    const int half = blockIdx.y;

    const float* Wt = half ? Wop_tag : Wap_tag;
    const float* bt = half ? bop_tag : bap_tag;
    for (int i = t; i < HID_ * TAGS_; i += 256) Wtag[i] = Wt[i];
    if (t < TAGS_) Btag[t] = bt[t];

    const int srow = t >> 2;
    const int skc  = (t & 3) * 8;
    const int NT = KEFF_ >> 5;   // 13

    f32x4 acc[4][4] = {};

    {
        #pragma unroll
        for (int q = 0; q < 2; ++q) {
            const short* g = A + (size_t)(bm + q * 64 + srow) * REDP_ + skc;
            GLOAD_LDS16(g, &lds[0][q * 2048 + wv * 512]);
        }
        #pragma unroll
        for (int q = 0; q < 2; ++q) {
            const short* g = Bt + (size_t)(bn + q * 64 + srow) * REDP_ + skc;
            GLOAD_LDS16(g, &lds[0][4096 + q * 2048 + wv * 512]);
        }
    }
    __syncthreads();

    int cur = 0;
    const int lr = ln & 15;
    const int lk = (ln >> 4) * 8;

    for (int kt = 0; kt < NT; ++kt) {
        if (kt + 1 < NT) {
            int k0 = (kt + 1) << 5;
            #pragma unroll
            for (int q = 0; q < 2; ++q) {
                const short* g = A + (size_t)(bm + q * 64 + srow) * REDP_ + k0 + skc;
                GLOAD_LDS16(g, &lds[cur ^ 1][q * 2048 + wv * 512]);
            }
            #pragma unroll
            for (int q = 0; q < 2; ++q) {
                const short* g = Bt + (size_t)(bn + q * 64 + srow) * REDP_ + k0 + skc;
                GLOAD_LDS16(g, &lds[cur ^ 1][4096 + q * 2048 + wv * 512]);
            }
        }

        const short* As = &lds[cur][0];
        const short* Bs = &lds[cur][4096];
        short8 a[4], b[4];
        #pragma unroll
        for (int fi = 0; fi < 4; ++fi)
            a[fi] = *(const short8*)(As + (wm * 64 + fi * 16 + lr) * 32 + lk);
        #pragma unroll
        for (int fj = 0; fj < 4; ++fj)
            b[fj] = *(const short8*)(Bs + (wn * 64 + fj * 16 + lr) * 32 + lk);
        #pragma unroll
        for (int fi = 0; fi < 4; ++fi)
            #pragma unroll
            for (int fj = 0; fj < 4; ++fj)
                acc[fi][fj] = __builtin_amdgcn_mfma_f32_16x16x32_bf16(
                    a[fi], b[fj], acc[fi][fj], 0, 0, 0);

        __syncthreads();
        cur ^= 1;
    }

    unsigned short* Co = half ? opOut : apOut;
    const int rl0 = wm * 64 + (ln >> 4) * 4;
    const int cl0 = wn * 64 + lr;
    #pragma unroll
    for (int fi = 0; fi < 4; ++fi)
        #pragma unroll
        for (int r = 0; r < 4; ++r) {
            int rl = rl0 + fi * 16 + r;
            #pragma unroll
            for (int fj = 0; fj < 4; ++fj) {
                int cl = cl0 + fj * 16;
                float v = fmaxf(acc[fi][fj][r] + bias[bn + cl], 0.f);
                Co[(size_t)(bm + rl) * 128 + cl] = f2bf(v);
                if (cl < 101) tagf[rl * 101 + cl] = v;
            }
        }
    __syncthreads();

    if (t < 128) {
        float s[TAGS_];
        #pragma unroll
        for (int g = 0; g < TAGS_; ++g) s[g] = Btag[g];
        const float* rowp = &tagf[t * 101];
        for (int k = 0; k < HID_; ++k) {
            float x = rowp[k];
            #pragma unroll
            for (int g = 0; g < TAGS_; ++g) s[g] += x * Wtag[k * TAGS_ + g];
        }
        float* o = out_tag + (size_t)half * (BL_ * TAGS_) + (size_t)(bm + t) * TAGS_;
        #pragma unroll
        for (int g = 0; g < TAGS_; ++g) o[g] = s[g];
    }
}

// ---------------------------------------------------------------------------
// 4) Fused biaffine + triplet (unchanged). grid (8 ip-tiles, 64 batches).
// ---------------------------------------------------------------------------
__global__ __launch_bounds__(256) void bi_triplet_kernel(
    const short* __restrict__ op, const short* __restrict__ ap,
    const short* __restrict__ WtBi, const float* __restrict__ bBi,
    float* __restrict__ out)
{
    __shared__ __align__(16) short As[16384];   // op j-tile, ks-subtiled
    __shared__ __align__(16) short Bs[16384];   // aff tile (built in phase A)
    __shared__ __align__(16) short Aap[4096];   // ap 32 rows, kf-subtiled

    const int t  = threadIdx.x;
    const int wv = t >> 6;
    const int ln = t & 63;
    const int wm = wv >> 1;
    const int wn = wv & 1;
    const int ipt = blockIdx.x;          // 0..7
    const int b   = blockIdx.y;          // 0..63

    const short* opB = op + (size_t)b * 256 * HIDP_;
    const short* apB = ap + ((size_t)b * 256 + ipt * 32) * HIDP_;

    const int rsub = ln >> 2;
    const int j8   = (ln & 3) * 8;

    // stage op j-tile 0 -> As, and ap 32 rows -> Aap
    #pragma unroll
    for (int i = 0; i < 8; ++i) {
        int ks = i >> 1, hf = i & 1;
        int rloc = wv * 32 + hf * 16;
        const short* gA = opB + (size_t)(rloc + rsub) * HIDP_ + ks * 32 + j8;
        GLOAD_LDS16(gA, &As[ks * 4096 + rloc * 32]);
    }
    #pragma unroll
    for (int q = 0; q < 2; ++q) {
        int kf   = q * 2 + (wv >> 1);
        int irow = (wv & 1) * 16 + (ln >> 2);
        const short* gA = apB + (size_t)irow * HIDP_ + kf * 32 + (ln & 3) * 8;
        GLOAD_LDS16(gA, &Aap[q * 2048 + wv * 512]);
    }
    __syncthreads();

    const int lr = ln & 15;
    const int lk = (ln >> 4) * 8;
    const int hbase = wv * 32;          // each wave owns 32 h-columns

    // A) aff sub-GEMM: M=32 (i), N=32/wave (h), K=128; 4 p-slices
    #pragma unroll
    for (int p = 0; p < 4; ++p) {
        f32x4 acc2[2][2] = {};
        const short* Wp = WtBi + (size_t)(p * 128) * HIDP_;
        #pragma unroll
        for (int kf = 0; kf < 4; ++kf) {
            short8 a2[2], b2[2];
            #pragma unroll
            for (int fm = 0; fm < 2; ++fm)
                a2[fm] = *(const short8*)(Aap + kf * 1024 + (fm * 16 + lr) * 32 + lk);
            #pragma unroll
            for (int fn = 0; fn < 2; ++fn)
                b2[fn] = *(const short8*)(Wp + (size_t)(hbase + fn * 16 + lr) * HIDP_ + kf * 32 + lk);
            #pragma unroll
            for (int fm = 0; fm < 2; ++fm)
                #pragma unroll
                for (int fn = 0; fn < 2; ++fn)
                    acc2[fm][fn] = __builtin_amdgcn_mfma_f32_16x16x32_bf16(
                        a2[fm], b2[fn], acc2[fm][fn], 0, 0, 0);
        }
        // deposit aff -> Bs (triplet B layout: row ip_local = i*4+p, k = h)
        #pragma unroll
        for (int fm = 0; fm < 2; ++fm)
            #pragma unroll
            for (int fn = 0; fn < 2; ++fn) {
                int h = hbase + fn * 16 + lr;
                float bias = bBi[p * 128 + h];
                #pragma unroll
                for (int r = 0; r < 4; ++r) {
                    int i = fm * 16 + (ln >> 4) * 4 + r;
                    float v = acc2[fm][fn][r] + bias;
                    Bs[(h >> 5) * 4096 + (i * 4 + p) * 32 + (h & 31)] = (short)f2bf(v);
                }
            }
    }
    __syncthreads();

    // C) triplet: two j-tiles vs Bs
    float* Ob = out + (size_t)b * 256 * 1024;
    #pragma unroll
    for (int jt = 0; jt < 2; ++jt) {
        f32x4 acc[4][4] = {};
        #pragma unroll
        for (int ks = 0; ks < 4; ++ks) {
            short8 a[4], bf[4];
            #pragma unroll
            for (int fi = 0; fi < 4; ++fi)
                a[fi] = *(const short8*)(As + ks * 4096 + (wm * 64 + fi * 16 + lr) * 32 + lk);
            #pragma unroll
            for (int fj = 0; fj < 4; ++fj)
                bf[fj] = *(const short8*)(Bs + ks * 4096 + (wn * 64 + fj * 16 + lr) * 32 + lk);
            #pragma unroll
            for (int fi = 0; fi < 4; ++fi)
                #pragma unroll
                for (int fj = 0; fj < 4; ++fj)
                    acc[fi][fj] = __builtin_amdgcn_mfma_f32_16x16x32_bf16(
                        a[fi], bf[fj], acc[fi][fj], 0, 0, 0);
        }

        if (jt == 0) {
            __syncthreads();   // all waves done reading As
            // restage op j-tile 1 while storing jt=0 results
            #pragma unroll
            for (int i = 0; i < 8; ++i) {
                int ks = i >> 1, hf = i & 1;
                int rloc = wv * 32 + hf * 16;
                const short* gA = opB + (size_t)(128 + rloc + rsub) * HIDP_ + ks * 32 + j8;
                GLOAD_LDS16(gA, &As[ks * 4096 + rloc * 32]);
            }
        }

        const int row0 = jt * 128 + wm * 64 + (ln >> 4) * 4;
        const int col0 = ipt * 128 + wn * 64 + lr;
        #pragma unroll
        for (int fi = 0; fi < 4; ++fi)
            #pragma unroll
            for (int r = 0; r < 4; ++r) {
                int row = row0 + fi * 16 + r;
                #pragma unroll
                for (int fj = 0; fj < 4; ++fj)
                    Ob[(size_t)row * 1024 + col0 + fj * 16] = acc[fi][fj][r];
            }

        if (jt == 0) __syncthreads();   // As(j=1) ready
    }
}

// ---------------------------------------------------------------------------
extern "C" void kernel_launch(void* const* d_in, const int* in_sizes, int n_in,
                              void* d_out, int out_size, void* d_ws, size_t ws_size,
                              hipStream_t stream)
{
    const float* bert     = (const float*)d_in[0];
    const int*   pos      = (const int*)  d_in[1];
    const float* W_reduc  = (const float*)d_in[2];
    const float* b_reduc  = (const float*)d_in[3];
    const float* W_ap     = (const float*)d_in[4];
    const float* b_ap     = (const float*)d_in[5];
    const float* W_op     = (const float*)d_in[6];
    const float* b_op     = (const float*)d_in[7];
    const float* W_ap_tag = (const float*)d_in[8];
    const float* b_ap_tag = (const float*)d_in[9];
    const float* W_op_tag = (const float*)d_in[10];
    const float* b_op_tag = (const float*)d_in[11];
    const float* W_bi     = (const float*)d_in[12];

    float* out = (float*)d_out;

    // Workspace layout (bytes; all 16B-aligned)
    char* ws = (char*)d_ws;
    unsigned short* pooled = (unsigned short*)ws; ws += (size_t)BL_ * D_ * 2;
    unsigned short* h      = (unsigned short*)ws; ws += (size_t)BL_ * REDP_ * 2;
    unsigned short* ap     = (unsigned short*)ws; ws += (size_t)BL_ * HIDP_ * 2;
    unsigned short* opv    = (unsigned short*)ws; ws += (size_t)BL_ * HIDP_ * 2;
    unsigned short* WtR    = (unsigned short*)ws; ws += (size_t)REDP_ * D_ * 2;
    unsigned short* WtAO   = (unsigned short*)ws; ws += (size_t)NAO_ * REDP_ * 2;
    unsigned short* WtBi   = (unsigned short*)ws; ws += (size_t)NBI_ * HIDP_ * 2;
    float* bR  = (float*)ws;  ws += REDP_ * 4;
    float* bAO = (float*)ws;  ws += NAO_ * 4;
    float* bBi = (float*)ws;  ws += NBI_ * 4;

    // 0+1) seg_mean + prep (one launch)
    front_kernel<<<SEG_BLOCKS + PREP_BLOCKS, 256, 0, stream>>>(
        bert, pos, pooled,
        W_reduc, b_reduc, W_ap, b_ap, W_op, b_op, W_bi,
        WtR, WtAO, WtBi, bR, bAO, bBi);

    // 2) h = relu(pooled @ W_reduc + b), 64x128 tiles, 1024 blocks
    gemm1_kernel<<<dim3(BL_ / 64, REDP_ / 128), 256, 0, stream>>>(
        (const short*)pooled, (const short*)WtR, bR, h);

    // 3) ap|op = relu(h @ [W_ap|W_op] + b) + tag heads (K=416, 13 tiles)
    gemm23_tag_kernel<<<dim3(BL_ / 128, 2), 256, 0, stream>>>(
        (const short*)h, (const short*)WtAO, bAO, ap, opv,
        W_ap_tag, b_ap_tag, W_op_tag, b_op_tag, out);

    // 4) fused biaffine + triplet -> out[163840 : ]
    bi_triplet_kernel<<<dim3(8, B_), 256, 0, stream>>>(
        (const short*)opv, (const short*)ap, (const short*)WtBi, bBi,
        out + 2 * BL_ * TAGS_);
}

// Round 18
// 77.169 us; speedup vs baseline: 1.1128x; 1.1128x over previous
//
#include <hip/hip_runtime.h>
#include <hip/hip_bf16.h>

// Problem constants
#define B_    64
#define S_    512
#define L_    256
#define D_    768      // K of GEMM1
#define RED_  400
#define REDP_ 512      // padded N of GEMM1 / K-stride of GEMM23
#define KEFF_ 416      // effective K of GEMM23 (13 k-tiles; h cols 400.. are 0)
#define HID_  100
#define HIDP_ 128      // padded N of GEMM23 / K of aff+triplet
#define TAGS_ 5
#define POL_  4
#define NBI_  512      // aff padded N (4 * 128)
#define NAO_  256      // fused ap|op GEMM N
#define BL_   (B_ * L_)  // 16384

typedef __attribute__((ext_vector_type(8))) short short8;
typedef __attribute__((ext_vector_type(4))) float f32x4;
typedef __attribute__((ext_vector_type(4))) unsigned short u16x4;

#define GLOAD_LDS16(gp, lp) __builtin_amdgcn_global_load_lds( \
    (const __attribute__((address_space(1))) void*)(gp),      \
    (__attribute__((address_space(3))) void*)(lp), 16, 0, 0)

__device__ inline float bf2f(unsigned short u) {
    union { unsigned int i; float f; } c; c.i = ((unsigned)u) << 16; return c.f;
}
__device__ inline unsigned short f2bf(float f) {
    __hip_bfloat16 h = __float2bfloat16(f);
    unsigned short u;
    __builtin_memcpy(&u, &h, 2);
    return u;
}

// ---------------------------------------------------------------------------
// 0) PREP: weight/bias prep only.
// ---------------------------------------------------------------------------
#define SZ0 393216
#define SZ1 131072
#define SZ2 65536
#define SZ3 512
#define SZ4 256
#define PREP_TOT (SZ0 + SZ1 + SZ2 + SZ3 + SZ4)
#define PREP_BLOCKS ((PREP_TOT + 255) / 256)

__global__ __launch_bounds__(256) void prep_kernel(
    const float* __restrict__ W_reduc, const float* __restrict__ b_reduc,
    const float* __restrict__ W_ap, const float* __restrict__ b_ap,
    const float* __restrict__ W_op, const float* __restrict__ b_op,
    const float* __restrict__ W_bi,
    unsigned short* __restrict__ WtR, unsigned short* __restrict__ WtAO,
    unsigned short* __restrict__ WtBi,
    float* __restrict__ bR, float* __restrict__ bAO, float* __restrict__ bBi)
{
    int idx = blockIdx.x * 256 + threadIdx.x;
    if (idx < SZ0) {
        int n = idx / D_, k = idx - n * D_;
        float v = (n < RED_) ? W_reduc[(size_t)k * RED_ + n] : 0.f;
        WtR[idx] = f2bf(v);
    } else if (idx < SZ0 + SZ1) {
        int i = idx - SZ0;
        int n = i >> 9, k = i & 511;
        float v = 0.f;
        if (k < RED_) {
            if (n < HID_)                      v = W_ap[(size_t)k * HID_ + n];
            else if (n >= 128 && n < 128+HID_) v = W_op[(size_t)k * HID_ + (n-128)];
        }
        WtAO[i] = f2bf(v);
    } else if (idx < SZ0 + SZ1 + SZ2) {
        int i = idx - SZ0 - SZ1;
        int n = i >> 7, k = i & 127;
        int p = n >> 7, h = n & 127;
        float v = (h < HID_ && k < HID_) ? W_bi[(size_t)k * RED_ + p * HID_ + h] : 0.f;
        WtBi[i] = f2bf(v);
        if (k == 0) bBi[n] = (h < HID_) ? W_bi[(size_t)HID_ * RED_ + p * HID_ + h] : 0.f;
    } else if (idx < SZ0 + SZ1 + SZ2 + SZ3) {
        int n = idx - SZ0 - SZ1 - SZ2;
        bR[n] = (n < RED_) ? b_reduc[n] : 0.f;
    } else if (idx < PREP_TOT) {
        int n = idx - SZ0 - SZ1 - SZ2 - SZ3;
        bAO[n] = (n < 128) ? ((n < HID_) ? b_ap[n] : 0.f)
                           : (((n-128) < HID_) ? b_op[n-128] : 0.f);
    }
}

// ---------------------------------------------------------------------------
// 1) GEMM1 + fused segment-mean, deep-A-prefetch (2 iterations):
//    h = relu( segmean(bert)[16384,768] @ WtR[512,768]^T + bR ) -> bf16
// Tile 64 rows x 256 cols; grid (256, 2) = 512 blocks (2 blocks/CU).
// A: TRIPLE-buffered LDS; loads for tile kt+2 issued at iter kt, converted
//    + ds_written during iter kt+1, consumed at kt+2 (2-iter latency cover).
// B: double-buffered via global_load_lds (1-iter prefetch, as m97).
// ---------------------------------------------------------------------------
__global__ __launch_bounds__(256) void gemm1_seg_kernel(
    const float* __restrict__ bert, const int* __restrict__ pos,
    const short* __restrict__ Bt, const float* __restrict__ bias,
    unsigned short* __restrict__ Co)
{
    __shared__ __align__(16) short ldsA[3][2048];   // A 64x32 per buf
    __shared__ __align__(16) short ldsB[2][8192];   // B 256x32 per buf

    const int t  = threadIdx.x;
    const int wv = t >> 6;
    const int ln = t & 63;
    const int bm  = blockIdx.x * 64;
    const int bnh = blockIdx.y * 256;
    const int batch = bm >> 8;     // 64 rows never cross a 256-row batch

    const int srow = t >> 2;       // 0..63
    const int skc  = (t & 3) * 8;  // k offset (elements)

    // span row bases for my A row
    const int r = bm + srow;
    const int s = pos[r * 2 + 0];
    const int e = pos[r * 2 + 1];  // e == s when len == 1 -> (a+a)*0.5 == a
    const size_t rb0 = ((size_t)batch * S_ + s) * D_;
    const size_t rb1 = ((size_t)batch * S_ + e) * D_;

    f32x4 acc[4][4] = {};
    const int NT = D_ >> 5;   // 24

    // ---- prologue ----
    {
        // B tile 0
        #pragma unroll
        for (int q = 0; q < 4; ++q) {
            const short* g = Bt + (size_t)(bnh + q * 64 + srow) * D_ + skc;
            GLOAD_LDS16(g, &ldsB[0][q * 2048 + wv * 512]);
        }
        // A tile 0: load + convert + write directly
        f32x4 x0 = *(const f32x4*)(bert + rb0 + skc);
        f32x4 x1 = *(const f32x4*)(bert + rb0 + skc + 4);
        f32x4 y0 = *(const f32x4*)(bert + rb1 + skc);
        f32x4 y1 = *(const f32x4*)(bert + rb1 + skc + 4);
        f32x4 s0 = (x0 + y0) * 0.5f;
        f32x4 s1 = (x1 + y1) * 0.5f;
        union { short8 v; unsigned short u[8]; } o;
        #pragma unroll
        for (int j = 0; j < 4; ++j) { o.u[j] = f2bf(s0[j]); o.u[4+j] = f2bf(s1[j]); }
        *(short8*)(&ldsA[0][srow * 32 + skc]) = o.v;
    }
    // A tile 1: load into held regs
    f32x4 hx0, hx1, hy0, hy1;
    {
        int col = 32 + skc;
        hx0 = *(const f32x4*)(bert + rb0 + col);
        hx1 = *(const f32x4*)(bert + rb0 + col + 4);
        hy0 = *(const f32x4*)(bert + rb1 + col);
        hy1 = *(const f32x4*)(bert + rb1 + col + 4);
    }
    __syncthreads();

    const int lr = ln & 15;
    const int lk = (ln >> 4) * 8;
    int ar = 0, aw = 1;   // A read / write buffer indices (mod 3)

    for (int kt = 0; kt < NT; ++kt) {
        const bool m1 = (kt + 1 < NT);
        const bool m2 = (kt + 2 < NT);

        // issue B gloads for kt+1
        if (m1) {
            int k0 = (kt + 1) << 5;
            #pragma unroll
            for (int q = 0; q < 4; ++q) {
                const short* g = Bt + (size_t)(bnh + q * 64 + srow) * D_ + k0 + skc;
                GLOAD_LDS16(g, &ldsB[(kt + 1) & 1][q * 2048 + wv * 512]);
            }
        }
        // issue A loads for kt+2 (2 iterations of latency cover)
        f32x4 nx0, nx1, ny0, ny1;
        if (m2) {
            int col = (kt + 2) * 32 + skc;
            nx0 = *(const f32x4*)(bert + rb0 + col);
            nx1 = *(const f32x4*)(bert + rb0 + col + 4);
            ny0 = *(const f32x4*)(bert + rb1 + col);
            ny1 = *(const f32x4*)(bert + rb1 + col + 4);
        }

        // MFMA phase
        const short* As = &ldsA[ar][0];
        const short* Bs = &ldsB[kt & 1][0];
        short8 a[4], b[4];
        #pragma unroll
        for (int fi = 0; fi < 4; ++fi)
            a[fi] = *(const short8*)(As + (fi * 16 + lr) * 32 + lk);
        #pragma unroll
        for (int fj = 0; fj < 4; ++fj)
            b[fj] = *(const short8*)(Bs + (wv * 64 + fj * 16 + lr) * 32 + lk);
        #pragma unroll
        for (int fi = 0; fi < 4; ++fi)
            #pragma unroll
            for (int fj = 0; fj < 4; ++fj)
                acc[fi][fj] = __builtin_amdgcn_mfma_f32_16x16x32_bf16(
                    a[fi], b[fj], acc[fi][fj], 0, 0, 0);

        // convert held regs (tile kt+1, loaded at iter kt-1) -> Abuf[aw]
        if (m1) {
            f32x4 s0 = (hx0 + hy0) * 0.5f;
            f32x4 s1 = (hx1 + hy1) * 0.5f;
            union { short8 v; unsigned short u[8]; } o;
            #pragma unroll
            for (int j = 0; j < 4; ++j) { o.u[j] = f2bf(s0[j]); o.u[4+j] = f2bf(s1[j]); }
            *(short8*)(&ldsA[aw][srow * 32 + skc]) = o.v;
        }

        __syncthreads();

        ar = aw;
        aw = (aw == 2) ? 0 : aw + 1;
        hx0 = nx0; hx1 = nx1; hy0 = ny0; hy1 = ny1;
    }

    const int row0 = bm + (ln >> 4) * 4;
    const int col0 = bnh + wv * 64 + lr;
    #pragma unroll
    for (int fi = 0; fi < 4; ++fi)
        #pragma unroll
        for (int rr = 0; rr < 4; ++rr) {
            int row = row0 + fi * 16 + rr;
            #pragma unroll
            for (int fj = 0; fj < 4; ++fj) {
                int col = col0 + fj * 16;
                float v = fmaxf(acc[fi][fj][rr] + bias[col], 0.f);
                Co[(size_t)row * REDP_ + col] = f2bf(v);
            }
        }
}

// ---------------------------------------------------------------------------
// 2) GEMM23 + tag heads (unchanged). grid (128, 2).
// ---------------------------------------------------------------------------
__global__ __launch_bounds__(256) void gemm23_tag_kernel(
    const short* __restrict__ A, const short* __restrict__ Bt,
    const float* __restrict__ bias,
    unsigned short* __restrict__ apOut, unsigned short* __restrict__ opOut,
    const float* __restrict__ Wap_tag, const float* __restrict__ bap_tag,
    const float* __restrict__ Wop_tag, const float* __restrict__ bop_tag,
    float* __restrict__ out_tag)
{
    __shared__ __align__(16) short lds[2][8192];
    __shared__ float tagf[128 * 101];
    __shared__ float Wtag[HID_ * TAGS_];
    __shared__ float Btag[TAGS_];

    const int t  = threadIdx.x;
    const int wv = t >> 6;
    const int ln = t & 63;
    const int wm = wv >> 1;
    const int wn = wv & 1;
    const int bm = blockIdx.x * 128;
    const int bn = blockIdx.y * 128;
    const int half = blockIdx.y;

    const float* Wt = half ? Wop_tag : Wap_tag;
    const float* bt = half ? bop_tag : bap_tag;
    for (int i = t; i < HID_ * TAGS_; i += 256) Wtag[i] = Wt[i];
    if (t < TAGS_) Btag[t] = bt[t];

    const int srow = t >> 2;
    const int skc  = (t & 3) * 8;
    const int NT = KEFF_ >> 5;   // 13

    f32x4 acc[4][4] = {};

    {
        #pragma unroll
        for (int q = 0; q < 2; ++q) {
            const short* g = A + (size_t)(bm + q * 64 + srow) * REDP_ + skc;
            GLOAD_LDS16(g, &lds[0][q * 2048 + wv * 512]);
        }
        #pragma unroll
        for (int q = 0; q < 2; ++q) {
            const short* g = Bt + (size_t)(bn + q * 64 + srow) * REDP_ + skc;
            GLOAD_LDS16(g, &lds[0][4096 + q * 2048 + wv * 512]);
        }
    }
    __syncthreads();

    int cur = 0;
    const int lr = ln & 15;
    const int lk = (ln >> 4) * 8;

    for (int kt = 0; kt < NT; ++kt) {
        if (kt + 1 < NT) {
            int k0 = (kt + 1) << 5;
            #pragma unroll
            for (int q = 0; q < 2; ++q) {
                const short* g = A + (size_t)(bm + q * 64 + srow) * REDP_ + k0 + skc;
                GLOAD_LDS16(g, &lds[cur ^ 1][q * 2048 + wv * 512]);
            }
            #pragma unroll
            for (int q = 0; q < 2; ++q) {
                const short* g = Bt + (size_t)(bn + q * 64 + srow) * REDP_ + k0 + skc;
                GLOAD_LDS16(g, &lds[cur ^ 1][4096 + q * 2048 + wv * 512]);
            }
        }

        const short* As = &lds[cur][0];
        const short* Bs = &lds[cur][4096];
        short8 a[4], b[4];
        #pragma unroll
        for (int fi = 0; fi < 4; ++fi)
            a[fi] = *(const short8*)(As + (wm * 64 + fi * 16 + lr) * 32 + lk);
        #pragma unroll
        for (int fj = 0; fj < 4; ++fj)
            b[fj] = *(const short8*)(Bs + (wn * 64 + fj * 16 + lr) * 32 + lk);
        #pragma unroll
        for (int fi = 0; fi < 4; ++fi)
            #pragma unroll
            for (int fj = 0; fj < 4; ++fj)
                acc[fi][fj] = __builtin_amdgcn_mfma_f32_16x16x32_bf16(
                    a[fi], b[fj], acc[fi][fj], 0, 0, 0);

        __syncthreads();
        cur ^= 1;
    }

    unsigned short* Co = half ? opOut : apOut;
    const int rl0 = wm * 64 + (ln >> 4) * 4;
    const int cl0 = wn * 64 + lr;
    #pragma unroll
    for (int fi = 0; fi < 4; ++fi)
        #pragma unroll
        for (int r = 0; r < 4; ++r) {
            int rl = rl0 + fi * 16 + r;
            #pragma unroll
            for (int fj = 0; fj < 4; ++fj) {
                int cl = cl0 + fj * 16;
                float v = fmaxf(acc[fi][fj][r] + bias[bn + cl], 0.f);
                Co[(size_t)(bm + rl) * 128 + cl] = f2bf(v);
                if (cl < 101) tagf[rl * 101 + cl] = v;
            }
        }
    __syncthreads();

    if (t < 128) {
        float sg[TAGS_];
        #pragma unroll
        for (int g = 0; g < TAGS_; ++g) sg[g] = Btag[g];
        const float* rowp = &tagf[t * 101];
        for (int k = 0; k < HID_; ++k) {
            float x = rowp[k];
            #pragma unroll
            for (int g = 0; g < TAGS_; ++g) sg[g] += x * Wtag[k * TAGS_ + g];
        }
        float* o = out_tag + (size_t)half * (BL_ * TAGS_) + (size_t)(bm + t) * TAGS_;
        #pragma unroll
        for (int g = 0; g < TAGS_; ++g) o[g] = sg[g];
    }
}

// ---------------------------------------------------------------------------
// 3) Fused biaffine + triplet (unchanged). grid (8 ip-tiles, 64 batches).
// ---------------------------------------------------------------------------
__global__ __launch_bounds__(256) void bi_triplet_kernel(
    const short* __restrict__ op, const short* __restrict__ ap,
    const short* __restrict__ WtBi, const float* __restrict__ bBi,
    float* __restrict__ out)
{
    __shared__ __align__(16) short As[16384];   // op j-tile, ks-subtiled
    __shared__ __align__(16) short Bs[16384];   // aff tile (built in phase A)
    __shared__ __align__(16) short Aap[4096];   // ap 32 rows, kf-subtiled

    const int t  = threadIdx.x;
    const int wv = t >> 6;
    const int ln = t & 63;
    const int wm = wv >> 1;
    const int wn = wv & 1;
    const int ipt = blockIdx.x;          // 0..7
    const int b   = blockIdx.y;          // 0..63

    const short* opB = op + (size_t)b * 256 * HIDP_;
    const short* apB = ap + ((size_t)b * 256 + ipt * 32) * HIDP_;

    const int rsub = ln >> 2;
    const int j8   = (ln & 3) * 8;

    // stage op j-tile 0 -> As, and ap 32 rows -> Aap
    #pragma unroll
    for (int i = 0; i < 8; ++i) {
        int ks = i >> 1, hf = i & 1;
        int rloc = wv * 32 + hf * 16;
        const short* gA = opB + (size_t)(rloc + rsub) * HIDP_ + ks * 32 + j8;
        GLOAD_LDS16(gA, &As[ks * 4096 + rloc * 32]);
    }
    #pragma unroll
    for (int q = 0; q < 2; ++q) {
        int kf   = q * 2 + (wv >> 1);
        int irow = (wv & 1) * 16 + (ln >> 2);
        const short* gA = apB + (size_t)irow * HIDP_ + kf * 32 + (ln & 3) * 8;
        GLOAD_LDS16(gA, &Aap[q * 2048 + wv * 512]);
    }
    __syncthreads();

    const int lr = ln & 15;
    const int lk = (ln >> 4) * 8;
    const int hbase = wv * 32;          // each wave owns 32 h-columns

    // A) aff sub-GEMM: M=32 (i), N=32/wave (h), K=128; 4 p-slices
    #pragma unroll
    for (int p = 0; p < 4; ++p) {
        f32x4 acc2[2][2] = {};
        const short* Wp = WtBi + (size_t)(p * 128) * HIDP_;
        #pragma unroll
        for (int kf = 0; kf < 4; ++kf) {
            short8 a2[2], b2[2];
            #pragma unroll
            for (int fm = 0; fm < 2; ++fm)
                a2[fm] = *(const short8*)(Aap + kf * 1024 + (fm * 16 + lr) * 32 + lk);
            #pragma unroll
            for (int fn = 0; fn < 2; ++fn)
                b2[fn] = *(const short8*)(Wp + (size_t)(hbase + fn * 16 + lr) * HIDP_ + kf * 32 + lk);
            #pragma unroll
            for (int fm = 0; fm < 2; ++fm)
                #pragma unroll
                for (int fn = 0; fn < 2; ++fn)
                    acc2[fm][fn] = __builtin_amdgcn_mfma_f32_16x16x32_bf16(
                        a2[fm], b2[fn], acc2[fm][fn], 0, 0, 0);
        }
        // deposit aff -> Bs (triplet B layout: row ip_local = i*4+p, k = h)
        #pragma unroll
        for (int fm = 0; fm < 2; ++fm)
            #pragma unroll
            for (int fn = 0; fn < 2; ++fn) {
                int h = hbase + fn * 16 + lr;
                float bias = bBi[p * 128 + h];
                #pragma unroll
                for (int r = 0; r < 4; ++r) {
                    int i = fm * 16 + (ln >> 4) * 4 + r;
                    float v = acc2[fm][fn][r] + bias;
                    Bs[(h >> 5) * 4096 + (i * 4 + p) * 32 + (h & 31)] = (short)f2bf(v);
                }
            }
    }
    __syncthreads();

    // C) triplet: two j-tiles vs Bs
    float* Ob = out + (size_t)b * 256 * 1024;
    #pragma unroll
    for (int jt = 0; jt < 2; ++jt) {
        f32x4 acc[4][4] = {};
        #pragma unroll
        for (int ks = 0; ks < 4; ++ks) {
            short8 a[4], bf[4];
            #pragma unroll
            for (int fi = 0; fi < 4; ++fi)
                a[fi] = *(const short8*)(As + ks * 4096 + (wm * 64 + fi * 16 + lr) * 32 + lk);
            #pragma unroll
            for (int fj = 0; fj < 4; ++fj)
                bf[fj] = *(const short8*)(Bs + ks * 4096 + (wn * 64 + fj * 16 + lr) * 32 + lk);
            #pragma unroll
            for (int fi = 0; fi < 4; ++fi)
                #pragma unroll
                for (int fj = 0; fj < 4; ++fj)
                    acc[fi][fj] = __builtin_amdgcn_mfma_f32_16x16x32_bf16(
                        a[fi], bf[fj], acc[fi][fj], 0, 0, 0);
        }

        if (jt == 0) {
            __syncthreads();   // all waves done reading As
            // restage op j-tile 1 while storing jt=0 results
            #pragma unroll
            for (int i = 0; i < 8; ++i) {
                int ks = i >> 1, hf = i & 1;
                int rloc = wv * 32 + hf * 16;
                const short* gA = opB + (size_t)(128 + rloc + rsub) * HIDP_ + ks * 32 + j8;
                GLOAD_LDS16(gA, &As[ks * 4096 + rloc * 32]);
            }
        }

        const int row0 = jt * 128 + wm * 64 + (ln >> 4) * 4;
        const int col0 = ipt * 128 + wn * 64 + lr;
        #pragma unroll
        for (int fi = 0; fi < 4; ++fi)
            #pragma unroll
            for (int r = 0; r < 4; ++r) {
                int row = row0 + fi * 16 + r;
                #pragma unroll
                for (int fj = 0; fj < 4; ++fj)
                    Ob[(size_t)row * 1024 + col0 + fj * 16] = acc[fi][fj][r];
            }

        if (jt == 0) __syncthreads();   // As(j=1) ready
    }
}

// ---------------------------------------------------------------------------
extern "C" void kernel_launch(void* const* d_in, const int* in_sizes, int n_in,
                              void* d_out, int out_size, void* d_ws, size_t ws_size,
                              hipStream_t stream)
{
    const float* bert     = (const float*)d_in[0];
    const int*   pos      = (const int*)  d_in[1];
    const float* W_reduc  = (const float*)d_in[2];
    const float* b_reduc  = (const float*)d_in[3];
    const float* W_ap     = (const float*)d_in[4];
    const float* b_ap     = (const float*)d_in[5];
    const float* W_op     = (const float*)d_in[6];
    const float* b_op     = (const float*)d_in[7];
    const float* W_ap_tag = (const float*)d_in[8];
    const float* b_ap_tag = (const float*)d_in[9];
    const float* W_op_tag = (const float*)d_in[10];
    const float* b_op_tag = (const float*)d_in[11];
    const float* W_bi     = (const float*)d_in[12];

    float* out = (float*)d_out;

    // Workspace layout (bytes; all 16B-aligned)
    char* ws = (char*)d_ws;
    unsigned short* h      = (unsigned short*)ws; ws += (size_t)BL_ * REDP_ * 2;
    unsigned short* ap     = (unsigned short*)ws; ws += (size_t)BL_ * HIDP_ * 2;
    unsigned short* opv    = (unsigned short*)ws; ws += (size_t)BL_ * HIDP_ * 2;
    unsigned short* WtR    = (unsigned short*)ws; ws += (size_t)REDP_ * D_ * 2;
    unsigned short* WtAO   = (unsigned short*)ws; ws += (size_t)NAO_ * REDP_ * 2;
    unsigned short* WtBi   = (unsigned short*)ws; ws += (size_t)NBI_ * HIDP_ * 2;
    float* bR  = (float*)ws;  ws += REDP_ * 4;
    float* bAO = (float*)ws;  ws += NAO_ * 4;
    float* bBi = (float*)ws;  ws += NBI_ * 4;

    // 0) weight/bias prep
    prep_kernel<<<PREP_BLOCKS, 256, 0, stream>>>(
        W_reduc, b_reduc, W_ap, b_ap, W_op, b_op, W_bi,
        WtR, WtAO, WtBi, bR, bAO, bBi);

    // 1) h = relu(segmean(bert) @ W_reduc + b), fused, deep-A-prefetch
    gemm1_seg_kernel<<<dim3(BL_ / 64, 2), 256, 0, stream>>>(
        bert, pos, (const short*)WtR, bR, h);

    // 2) ap|op = relu(h @ [W_ap|W_op] + b) + tag heads (K=416, 13 tiles)
    gemm23_tag_kernel<<<dim3(BL_ / 128, 2), 256, 0, stream>>>(
        (const short*)h, (const short*)WtAO, bAO, ap, opv,
        W_ap_tag, b_ap_tag, W_op_tag, b_op_tag, out);

    // 3) fused biaffine + triplet -> out[163840 : ]
    bi_triplet_kernel<<<dim3(8, B_), 256, 0, stream>>>(
        (const short*)opv, (const short*)ap, (const short*)WtBi, bBi,
        out + 2 * BL_ * TAGS_);
}